// Round 7
// baseline (306.904 us; speedup 1.0000x reference)
//
#include <hip/hip_runtime.h>
#include <hip/hip_cooperative_groups.h>
#include <hip/hip_bf16.h>
#include <cstdint>
#include <cstddef>

#define AS1 __attribute__((address_space(1)))
#define AS3 __attribute__((address_space(3)))

namespace cg = cooperative_groups;

typedef __bf16 bf16;
typedef __bf16 bf16x4 __attribute__((ext_vector_type(4)));
typedef __bf16 bf16x8 __attribute__((ext_vector_type(8)));
typedef float f32x4 __attribute__((ext_vector_type(4)));

static constexpr int M_ROWS = 4096;
static constexpr int N_COLS = 1024;
static constexpr int IN_F   = 1024;
static constexpr int K2     = IN_F * 9;   // 9216: [silu(x) | 8 bases per i]
static constexpr int BK     = 32;         // fallback K-step
static constexpr int KT_CNT = K2 / BK;    // 288 (fallback)

static constexpr int GBK = 64;            // gemm K-step: rows are 128 B = 32 banks
static constexpr int GKT = K2 / GBK;      // 144

// Interface (R8 beacon): inputs f32, dict order, sizes in elements, out f32.

// Closed-form cardinal cubic B-spline over uniform knots t[j] = -2.2 + 0.4*j.
__device__ __forceinline__ void bases8(float x, float w8[8]) {
  float mf = x * 2.5f + 5.5f;           // (x - t0) / h
  int   m  = (int)floorf(mf);
  float u  = mf - (float)m;
  float u2 = u * u, u3 = u2 * u;
  float omu = 1.0f - u;
  const float s = 1.0f / 6.0f;
  float p0 = u3 * s;
  float p1 = (-3.f*u3 + 3.f*u2 + 3.f*u + 1.f) * s;
  float p2 = (3.f*u3 - 6.f*u2 + 4.f) * s;
  float p3 = omu * omu * omu * s;
  bool in = (m >= 0) && (m < 11);
#pragma unroll
  for (int j = 0; j < 8; ++j) {
    float v = 0.0f;
    v = (j == m)     ? p0 : v;
    v = (j == m - 1) ? p1 : v;
    v = (j == m - 2) ? p2 : v;
    v = (j == m - 3) ? p3 : v;
    w8[j] = in ? v : 0.0f;
  }
}

// ---------------------------------------------------------------------------
// Prep bodies (R17 vectorized, 4 elems per call).
// ---------------------------------------------------------------------------
__device__ __forceinline__ void expand4(const float* __restrict__ x,
                                        bf16* __restrict__ A, int t) {
  const int b  = t >> 8;                        // row (1024/4 groups/row)
  const int i0 = (t & 255) * 4;
  const float4 xv4 = *(const float4*)(x + (size_t)b * IN_F + i0);
  const float xs[4] = {xv4.x, xv4.y, xv4.z, xv4.w};

  bf16x4 sil;
  bf16* arow = A + (size_t)b * K2;
#pragma unroll
  for (int j = 0; j < 4; ++j) {
    float xv = xs[j];
    sil[j] = (bf16)(xv / (1.0f + __expf(-xv)));
    float w8[8];
    bases8(xv, w8);
    bf16x8 outv;
#pragma unroll
    for (int k = 0; k < 8; ++k) outv[k] = (bf16)w8[k];
    *(bf16x8*)(arow + IN_F + (size_t)(i0 + j) * 8) = outv;
  }
  *(bf16x4*)(arow + i0) = sil;
}

__device__ __forceinline__ void makebt4(const float* __restrict__ bw,
                                        const float* __restrict__ sw,
                                        const float* __restrict__ sc,
                                        bf16* __restrict__ BT, int t) {
  const int o  = t >> 8;
  const int i0 = (t & 255) * 4;
  const float4 bv4 = *(const float4*)(bw + (size_t)o * IN_F + i0);
  const float4 sc4 = *(const float4*)(sc + (size_t)o * IN_F + i0);
  const float bs[4] = {bv4.x, bv4.y, bv4.z, bv4.w};
  const float ss[4] = {sc4.x, sc4.y, sc4.z, sc4.w};

  bf16x4 base;
  bf16* brow = BT + (size_t)o * K2;
#pragma unroll
  for (int j = 0; j < 4; ++j) {
    base[j] = (bf16)bs[j];
    const float4* swp = (const float4*)(sw + ((size_t)o * IN_F + i0 + j) * 8);
    float4 a = swp[0], c = swp[1];
    float wv[8] = {a.x, a.y, a.z, a.w, c.x, c.y, c.z, c.w};
    bf16x8 r;
#pragma unroll
    for (int k = 0; k < 8; ++k) r[k] = (bf16)(wv[k] * ss[j]);
    *(bf16x8*)(brow + IN_F + (size_t)(i0 + j) * 8) = r;
  }
  *(bf16x4*)(brow + i0) = base;
}

__device__ __forceinline__ void prep_body(
    const float* __restrict__ x, const float* __restrict__ bw,
    const float* __restrict__ sw, const float* __restrict__ sc,
    bf16* __restrict__ A, bf16* __restrict__ BT) {
  const int nthr = gridDim.x * blockDim.x;
  const int tid0 = blockIdx.x * blockDim.x + threadIdx.x;
  const int NE = (M_ROWS * IN_F) / 4;
  const int NB = (N_COLS * IN_F) / 4;
  for (int t = tid0; t < NE; t += nthr) expand4(x, A, t);
  for (int t = tid0; t < NB; t += nthr) makebt4(bw, sw, sc, BT, t);
}

// ---------------------------------------------------------------------------
// GEMM body (R15 VERBATIM — best measured 80.5 µs / 957 TF / MfmaUtil 38%).
// 8-phase schedule: per K-tile 4 phases; phase = {ds_reads for quadrant |
// stage 1 half-tile | barrier | lgkmcnt(0)+sched_barrier | setprio(1)
// 16 MFMA setprio(0) | barrier}. ONE vmcnt(2) per tile at P3. Swizzle
// chunk^=(row&7) both sides (0 conflicts measured). Split-K xS, XCD map b&15.
// ---------------------------------------------------------------------------
__device__ __forceinline__ void gemm256_body(
    const bf16* __restrict__ A, const bf16* __restrict__ BT,
    float* __restrict__ P, int kt_seg) {
  __shared__ bf16 As[2][256 * GBK];   // 2 x 32 KB
  __shared__ bf16 Bs[2][256 * GBK];   // 2 x 32 KB  (128 KB)

  const int tid  = threadIdx.x;
  const int lane = tid & 63;
  const int w    = tid >> 6;          // 0..7

  const int b     = blockIdx.x;
  const int mtile = b & 15;           // XCD = b&7 = mtile&7 -> A pinned
  const int np    = (b >> 4) & 3;
  const int seg   = b >> 6;
  const int row0  = mtile * 256;
  const int col0  = np * 256;
  const int kt0   = seg * kt_seg;
  float* __restrict__ dst = P + (size_t)seg * M_ROWS * N_COLS;

  const int srow = lane >> 3;
  const int sch  = ((lane & 7) ^ srow) * 8;

  const int r  = lane & 15;
  const int q  = lane >> 4;
  const int wm = (w >> 2) * 128;
  const int wn = (w & 3) * 64;
  const int kc0 = ((0 + q) ^ (r & 7)) * 8;
  const int kc1 = ((4 + q) ^ (r & 7)) * 8;

  const bf16* aB = A  + (size_t)row0 * K2;
  const bf16* bB = BT + (size_t)col0 * K2;

  f32x4 acc[8][4];
#pragma unroll
  for (int mt = 0; mt < 8; ++mt)
#pragma unroll
    for (int nt = 0; nt < 4; ++nt)
      acc[mt][nt] = f32x4{0.f, 0.f, 0.f, 0.f};

  auto stageA = [&](int sbuf, int h, int kt) {
#pragma unroll
    for (int t8 = 0; t8 < 2; ++t8) {
      const int rg = h * 128 + w * 16 + t8 * 8;
      const bf16* ga = aB + (size_t)(rg + srow) * K2 + kt * GBK + sch;
      __builtin_amdgcn_global_load_lds((const AS1 void*)ga,
                                       (AS3 void*)&As[sbuf][rg * GBK], 16, 0, 0);
    }
  };
  auto stageB = [&](int sbuf, int h, int kt) {
#pragma unroll
    for (int t8 = 0; t8 < 2; ++t8) {
      const int rg = h * 128 + w * 16 + t8 * 8;
      const bf16* gb = bB + (size_t)(rg + srow) * K2 + kt * GBK + sch;
      __builtin_amdgcn_global_load_lds((const AS1 void*)gb,
                                       (AS3 void*)&Bs[sbuf][rg * GBK], 16, 0, 0);
    }
  };

  // Prologue: tile0 fully + tile1's A-lo (= steady-state P3(t-1) slot).
  stageA(0, 0, kt0); stageA(0, 1, kt0);
  stageB(0, 0, kt0); stageB(0, 1, kt0);
  if (kt_seg > 1) stageA(1, 0, kt0 + 1);
  if (kt_seg > 1) asm volatile("s_waitcnt vmcnt(2)" ::: "memory");
  else            asm volatile("s_waitcnt vmcnt(0)" ::: "memory");
  __builtin_amdgcn_s_barrier();

  bf16x8 af[4][2], bfr[4][2];

  for (int t = 0; t < kt_seg; ++t) {
    const int buf = t & 1, nbuf = buf ^ 1;
    const bf16* as = As[buf];
    const bf16* bs = Bs[buf];
    const bool sN = (t + 1 < kt_seg);   // stage tile t+1 exists

    // ---- P0: reads af(mt0-3)+bfr(nt0-1) [12]; stage(t+1, A-hi); Q0 ----
#pragma unroll
    for (int j = 0; j < 4; ++j) {
      const bf16* ar = &as[(wm + j * 16 + r) * GBK];
      af[j][0] = *(const bf16x8*)&ar[kc0];
      af[j][1] = *(const bf16x8*)&ar[kc1];
    }
#pragma unroll
    for (int j = 0; j < 2; ++j) {
      const bf16* br = &bs[(wn + j * 16 + r) * GBK];
      bfr[j][0] = *(const bf16x8*)&br[kc0];
      bfr[j][1] = *(const bf16x8*)&br[kc1];
    }
    if (sN) stageA(nbuf, 1, kt0 + t + 1);
    asm volatile("s_waitcnt lgkmcnt(8)" ::: "memory");
    __builtin_amdgcn_s_barrier();
    asm volatile("s_waitcnt lgkmcnt(0)" ::: "memory");
    __builtin_amdgcn_sched_barrier(0);
    __builtin_amdgcn_s_setprio(1);
#pragma unroll
    for (int j = 0; j < 4; ++j)
#pragma unroll
      for (int n = 0; n < 2; ++n) {
        acc[j][n] = __builtin_amdgcn_mfma_f32_16x16x32_bf16(af[j][0], bfr[n][0], acc[j][n], 0, 0, 0);
        acc[j][n] = __builtin_amdgcn_mfma_f32_16x16x32_bf16(af[j][1], bfr[n][1], acc[j][n], 0, 0, 0);
      }
    __builtin_amdgcn_s_setprio(0);
    __builtin_amdgcn_s_barrier();

    // ---- P1: reads bfr(nt2-3) [4]; stage(t+1, B-lo); Q1 ----
#pragma unroll
    for (int j = 0; j < 2; ++j) {
      const bf16* br = &bs[(wn + (2 + j) * 16 + r) * GBK];
      bfr[2 + j][0] = *(const bf16x8*)&br[kc0];
      bfr[2 + j][1] = *(const bf16x8*)&br[kc1];
    }
    if (sN) stageB(nbuf, 0, kt0 + t + 1);
    __builtin_amdgcn_s_barrier();
    asm volatile("s_waitcnt lgkmcnt(0)" ::: "memory");
    __builtin_amdgcn_sched_barrier(0);
    __builtin_amdgcn_s_setprio(1);
#pragma unroll
    for (int j = 0; j < 4; ++j)
#pragma unroll
      for (int n = 0; n < 2; ++n) {
        acc[j][2 + n] = __builtin_amdgcn_mfma_f32_16x16x32_bf16(af[j][0], bfr[2 + n][0], acc[j][2 + n], 0, 0, 0);
        acc[j][2 + n] = __builtin_amdgcn_mfma_f32_16x16x32_bf16(af[j][1], bfr[2 + n][1], acc[j][2 + n], 0, 0, 0);
      }
    __builtin_amdgcn_s_setprio(0);
    __builtin_amdgcn_s_barrier();

    // ---- P2: reads af(mt4-7) [8]; stage(t+1, B-hi); Q2 ----
#pragma unroll
    for (int j = 0; j < 4; ++j) {
      const bf16* ar = &as[(wm + (4 + j) * 16 + r) * GBK];
      af[j][0] = *(const bf16x8*)&ar[kc0];
      af[j][1] = *(const bf16x8*)&ar[kc1];
    }
    if (sN) stageB(nbuf, 1, kt0 + t + 1);
    __builtin_amdgcn_s_barrier();
    asm volatile("s_waitcnt lgkmcnt(0)" ::: "memory");
    __builtin_amdgcn_sched_barrier(0);
    __builtin_amdgcn_s_setprio(1);
#pragma unroll
    for (int j = 0; j < 4; ++j)
#pragma unroll
      for (int n = 0; n < 2; ++n) {
        acc[4 + j][n] = __builtin_amdgcn_mfma_f32_16x16x32_bf16(af[j][0], bfr[n][0], acc[4 + j][n], 0, 0, 0);
        acc[4 + j][n] = __builtin_amdgcn_mfma_f32_16x16x32_bf16(af[j][1], bfr[n][1], acc[4 + j][n], 0, 0, 0);
      }
    __builtin_amdgcn_s_setprio(0);
    __builtin_amdgcn_s_barrier();

    // ---- P3: no reads; stage(t+2, A-lo) into freed buf; vmcnt; Q3 ----
    if (t + 2 < kt_seg) stageA(buf, 0, kt0 + t + 2);
    if (sN) {
      if (t + 2 < kt_seg) asm volatile("s_waitcnt vmcnt(2)" ::: "memory");
      else                asm volatile("s_waitcnt vmcnt(0)" ::: "memory");
    }
    __builtin_amdgcn_s_barrier();
    __builtin_amdgcn_s_setprio(1);
#pragma unroll
    for (int j = 0; j < 4; ++j)
#pragma unroll
      for (int n = 0; n < 2; ++n) {
        acc[4 + j][2 + n] = __builtin_amdgcn_mfma_f32_16x16x32_bf16(af[j][0], bfr[2 + n][0], acc[4 + j][2 + n], 0, 0, 0);
        acc[4 + j][2 + n] = __builtin_amdgcn_mfma_f32_16x16x32_bf16(af[j][1], bfr[2 + n][1], acc[4 + j][2 + n], 0, 0, 0);
      }
    __builtin_amdgcn_s_setprio(0);
    __builtin_amdgcn_s_barrier();
  }

  // f32 epilogue: C/D layout col = lane&15, row = (lane>>4)*4 + reg
#pragma unroll
  for (int mt = 0; mt < 8; ++mt)
#pragma unroll
    for (int nt = 0; nt < 4; ++nt)
#pragma unroll
      for (int k = 0; k < 4; ++k) {
        int row = row0 + wm + mt * 16 + q * 4 + k;
        int col = col0 + wn + nt * 16 + r;
        dst[(size_t)row * N_COLS + col] = acc[mt][nt][k];
      }
}

// ---------------------------------------------------------------------------
// Reduce body: out = sum of S planes, grid-stride f32x4.
// ---------------------------------------------------------------------------
__device__ __forceinline__ void reduce_body(const float* __restrict__ P,
                                            float* __restrict__ out, int segs) {
  const size_t plane = (size_t)M_ROWS * N_COLS / 4;
  const f32x4* p = (const f32x4*)P;
  f32x4* o = (f32x4*)out;
  const size_t stride = (size_t)gridDim.x * blockDim.x;
  for (size_t i = (size_t)blockIdx.x * blockDim.x + threadIdx.x; i < plane;
       i += stride) {
    if (segs == 4) {
      f32x4 a = p[i] + p[plane + i];
      f32x4 c = p[2 * plane + i] + p[3 * plane + i];
      o[i] = a + c;
    } else {
      f32x4 a = p[i];
      for (int s = 1; s < segs; ++s) a += p[(size_t)s * plane + i];
      o[i] = a;
    }
  }
}

// ---------------------------------------------------------------------------
// Kernel (R18): SINGLE cooperative dispatch — prep | grid.sync | gemm |
// grid.sync | reduce. R13-R17 showed non-gemm residue 122±6 µs vs a ~29 µs
// BW model for prep+reduce -> per-dispatch overhead dominates (R12 3-disp
// = 105, R13+ 4-disp = ~120). Grid S*64 <= 256 blocks @ 128 KB LDS = 1
// block/CU co-resident (cooperative-safe). CG grid sync carries device-scope
// fences (cross-XCD L2 visibility, G16).
// ---------------------------------------------------------------------------
__global__ __launch_bounds__(512, 2) void kan_mono(
    const float* __restrict__ x, const float* __restrict__ bw,
    const float* __restrict__ sw, const float* __restrict__ sc,
    bf16* __restrict__ A, bf16* __restrict__ BT,
    float* __restrict__ P, float* __restrict__ out, int kt_seg) {
  prep_body(x, bw, sw, sc, A, BT);
  cg::this_grid().sync();
  gemm256_body(A, BT, P, kt_seg);
  cg::this_grid().sync();
  reduce_body(P, out, gridDim.x >> 6);
}

// ---------------------------------------------------------------------------
// Standalone kernels (3-dispatch fallback if cooperative launch unavailable).
// ---------------------------------------------------------------------------
__global__ __launch_bounds__(512) void prep4(
    const float* __restrict__ x, const float* __restrict__ bw,
    const float* __restrict__ sw, const float* __restrict__ sc,
    bf16* __restrict__ A, bf16* __restrict__ BT) {
  prep_body(x, bw, sw, sc, A, BT);
}

__global__ __launch_bounds__(512, 2) void gemm256_8p(
    const bf16* __restrict__ A, const bf16* __restrict__ BT,
    float* __restrict__ P, int kt_seg) {
  gemm256_body(A, BT, P, kt_seg);
}

__global__ __launch_bounds__(256) void reduce_addN(
    const float* __restrict__ P, float* __restrict__ out, int segs) {
  reduce_body(P, out, segs);
}

// Scalar bodies kept for the slab fallback path.
__device__ __forceinline__ void expand_body(const float* __restrict__ x,
                                            bf16* __restrict__ A, int gid, int r0) {
  int b = gid >> 10;
  int i = gid & 1023;
  float xv = x[(size_t)r0 * IN_F + (size_t)gid];
  A[(size_t)b * K2 + i] = (bf16)(xv / (1.0f + __expf(-xv)));
  float w8[8];
  bases8(xv, w8);
  bf16x8 outv;
#pragma unroll
  for (int j = 0; j < 8; ++j) outv[j] = (bf16)w8[j];
  *(bf16x8*)(A + (size_t)b * K2 + IN_F + (size_t)i * 8) = outv;
}

__device__ __forceinline__ void makebt_body(const float* __restrict__ bw,
                                            const float* __restrict__ sw,
                                            const float* __restrict__ sc,
                                            bf16* __restrict__ BT, int gid) {
  int o = gid >> 10;
  int i = gid & 1023;
  BT[(size_t)o * K2 + i] = (bf16)bw[gid];
  float scale = sc[gid];
  const float4* swp = (const float4*)(sw + (size_t)gid * 8);
  float4 a = swp[0], b4 = swp[1];
  float wv[8] = {a.x, a.y, a.z, a.w, b4.x, b4.y, b4.z, b4.w};
  bf16x8 r;
#pragma unroll
  for (int j = 0; j < 8; ++j) r[j] = (bf16)(wv[j] * scale);
  *(bf16x8*)(BT + (size_t)o * K2 + IN_F + (size_t)i * 8) = r;
}

__global__ void expand_a(const float* __restrict__ x, bf16* __restrict__ A, int r0) {
  expand_body(x, A, blockIdx.x * blockDim.x + threadIdx.x, r0);
}
__global__ void make_bt(const float* __restrict__ bw, const float* __restrict__ sw,
                        const float* __restrict__ sc, bf16* __restrict__ BT) {
  makebt_body(bw, sw, sc, BT, blockIdx.x * blockDim.x + threadIdx.x);
}

// ---------------------------------------------------------------------------
// Kernel 3b (R13's 128x128 gemm, kept for fallback slab path).
// ---------------------------------------------------------------------------
__global__ __launch_bounds__(256, 2) void gemm_fused(
    const bf16* __restrict__ A, const bf16* __restrict__ BT,
    float* __restrict__ d0, float* __restrict__ d1,
    int r0, int mt_cnt, int kt_seg) {
  __shared__ bf16 As[2][128 * GBK];
  __shared__ bf16 Bs[2][128 * GBK];

  const int tid  = threadIdx.x;
  const int lane = tid & 63;
  const int w    = tid >> 6;

  const int bps = mt_cnt * 8;
  int b   = blockIdx.x;
  const int seg = b / bps;
  b -= seg * bps;
  const int row0 = (b % mt_cnt) * 128;
  const int col0 = (b / mt_cnt) * 128;
  float* __restrict__ dst = seg ? d1 : d0;
  const int kt0 = seg * kt_seg;

  const int srow = lane >> 3;
  const int sch  = ((lane & 7) ^ srow) * 8;
  const int r  = lane & 15;
  const int q  = lane >> 4;
  const int wm = (w >> 1) * 64;
  const int wn = (w & 1) * 64;
  const int kc0 = ((0 + q) ^ (r & 7)) * 8;
  const int kc1 = ((4 + q) ^ (r & 7)) * 8;

  const bf16* aB = A  + (size_t)row0 * K2;
  const bf16* bB = BT + (size_t)col0 * K2;

  f32x4 acc[4][4];
#pragma unroll
  for (int mt = 0; mt < 4; ++mt)
#pragma unroll
    for (int nt = 0; nt < 4; ++nt)
      acc[mt][nt] = f32x4{0.f, 0.f, 0.f, 0.f};

  auto stage = [&](int sbuf, int kt) {
#pragma unroll
    for (int t = 0; t < 4; ++t) {
      const int rg = w * 32 + t * 8;
      const bf16* ga = aB + (size_t)(rg + srow) * K2 + kt * GBK + sch;
      __builtin_amdgcn_global_load_lds((const AS1 void*)ga,
                                       (AS3 void*)&As[sbuf][rg * GBK], 16, 0, 0);
      const bf16* gb = bB + (size_t)(rg + srow) * K2 + kt * GBK + sch;
      __builtin_amdgcn_global_load_lds((const AS1 void*)gb,
                                       (AS3 void*)&Bs[sbuf][rg * GBK], 16, 0, 0);
    }
  };

  stage(0, kt0);
  int buf = 0;
  for (int i = 0; i < kt_seg; ++i) {
    if (i + 1 < kt_seg) {
      stage(buf ^ 1, kt0 + i + 1);
      asm volatile("s_waitcnt vmcnt(8)" ::: "memory");
    } else {
      asm volatile("s_waitcnt vmcnt(0)" ::: "memory");
    }
    __builtin_amdgcn_s_barrier();
    __builtin_amdgcn_sched_barrier(0);

    const bf16* as = As[buf];
    const bf16* bs = Bs[buf];

#pragma unroll
    for (int kk = 0; kk < 2; ++kk) {
      const int kc = kk ? kc1 : kc0;
      bf16x8 af[4], bfr[4];
#pragma unroll
      for (int mt = 0; mt < 4; ++mt)
        af[mt] = *(const bf16x8*)&as[(wm + mt * 16 + r) * GBK + kc];
#pragma unroll
      for (int nt = 0; nt < 4; ++nt)
        bfr[nt] = *(const bf16x8*)&bs[(wn + nt * 16 + r) * GBK + kc];
#pragma unroll
      for (int mt = 0; mt < 4; ++mt)
#pragma unroll
        for (int nt = 0; nt < 4; ++nt)
          acc[mt][nt] = __builtin_amdgcn_mfma_f32_16x16x32_bf16(
              af[mt], bfr[nt], acc[mt][nt], 0, 0, 0);
    }
    __builtin_amdgcn_s_barrier();
    buf ^= 1;
  }

#pragma unroll
  for (int mt = 0; mt < 4; ++mt)
#pragma unroll
    for (int nt = 0; nt < 4; ++nt)
#pragma unroll
      for (int k = 0; k < 4; ++k) {
        int row = r0 + row0 + wm + mt * 16 + q * 4 + k;
        int col = col0 + wn + nt * 16 + r;
        dst[(size_t)row * N_COLS + col] = acc[mt][nt][k];
      }
}

// ---------------------------------------------------------------------------
// Fallback (ws too small — not expected; SL=4096 confirmed in R9/R10).
// ---------------------------------------------------------------------------
__global__ __launch_bounds__(256) void kan_fused_fallback(
    const float* __restrict__ x, const float* __restrict__ bw,
    const float* __restrict__ sw, const float* __restrict__ sc,
    float* __restrict__ out) {
  __shared__ bf16 As[64 * BK];
  __shared__ bf16 Bs[128 * BK];
  const int tid  = threadIdx.x;
  const int lane = tid & 63;
  const int w    = tid >> 6;
  const int col0 = blockIdx.x * 128;
  const int row0 = blockIdx.y * 64;
  const int srow = tid >> 2, sq = tid & 3;
  const int r = lane & 15, q = lane >> 4, wn = w * 32;

  f32x4 acc[4][2];
#pragma unroll
  for (int mt = 0; mt < 4; ++mt)
#pragma unroll
    for (int nt = 0; nt < 2; ++nt) acc[mt][nt] = f32x4{0,0,0,0};

  for (int kt = 0; kt < KT_CNT; ++kt) {
    if (kt < 32) {
      const int cc = sq * 8;
      const float4* xp = (const float4*)(x + (size_t)(row0+srow)*IN_F + kt*BK + cc);
      float4 a = xp[0], b4 = xp[1];
      float xv[8] = {a.x,a.y,a.z,a.w,b4.x,b4.y,b4.z,b4.w};
      bf16x8 av;
#pragma unroll
      for (int j = 0; j < 8; ++j) av[j] = (bf16)(xv[j] / (1.0f + __expf(-xv[j])));
      *(bf16x8*)&As[srow * BK + cc] = av;
#pragma unroll
      for (int h = 0; h < 2; ++h) {
        const float4* bp = (const float4*)(bw + (size_t)(col0+h*64+srow)*IN_F + kt*BK + cc);
        float4 c0 = bp[0], c1 = bp[1];
        float bv[8] = {c0.x,c0.y,c0.z,c0.w,c1.x,c1.y,c1.z,c1.w};
        bf16x8 bb;
#pragma unroll
        for (int j = 0; j < 8; ++j) bb[j] = (bf16)bv[j];
        *(bf16x8*)&Bs[(h*64+srow)*BK + cc] = bb;
      }
    } else {
      const int i = (kt - 32) * 4 + sq;
      float xv = x[(size_t)(row0+srow)*IN_F + i];
      float w8[8]; bases8(xv, w8);
      bf16x8 av;
#pragma unroll
      for (int j = 0; j < 8; ++j) av[j] = (bf16)w8[j];
      *(bf16x8*)&As[srow * BK + sq * 8] = av;
#pragma unroll
      for (int h = 0; h < 2; ++h) {
        const int o = col0 + h*64 + srow;
        float s1 = sc[(size_t)o*IN_F + i];
        const float4* sp = (const float4*)(sw + ((size_t)o*IN_F + i)*8);
        float4 c0 = sp[0], c1 = sp[1];
        float wv[8] = {c0.x,c0.y,c0.z,c0.w,c1.x,c1.y,c1.z,c1.w};
        bf16x8 bb;
#pragma unroll
        for (int j = 0; j < 8; ++j) bb[j] = (bf16)(wv[j]*s1);
        *(bf16x8*)&Bs[(h*64+srow)*BK + sq*8] = bb;
      }
    }
    __syncthreads();
    bf16x8 af[4], bfr[2];
#pragma unroll
    for (int mt = 0; mt < 4; ++mt)
      af[mt] = *(const bf16x8*)&As[(mt*16+r)*BK + q*8];
#pragma unroll
    for (int nt = 0; nt < 2; ++nt)
      bfr[nt] = *(const bf16x8*)&Bs[(wn+nt*16+r)*BK + q*8];
#pragma unroll
    for (int mt = 0; mt < 4; ++mt)
#pragma unroll
      for (int nt = 0; nt < 2; ++nt)
        acc[mt][nt] = __builtin_amdgcn_mfma_f32_16x16x32_bf16(af[mt], bfr[nt], acc[mt][nt], 0,0,0);
    __syncthreads();
  }
#pragma unroll
  for (int mt = 0; mt < 4; ++mt)
#pragma unroll
    for (int nt = 0; nt < 2; ++nt)
#pragma unroll
      for (int k = 0; k < 4; ++k)
        out[(size_t)(row0+mt*16+q*4+k)*N_COLS + col0+wn+nt*16+r] = acc[mt][nt][k];
}

extern "C" void kernel_launch(void* const* d_in, const int* in_sizes, int n_in,
                              void* d_out, int out_size, void* d_ws, size_t ws_size,
                              hipStream_t stream) {
  const float* x    = (const float*)d_in[0];
  const float* bw   = (const float*)d_in[1];
  const float* sw   = (const float*)d_in[2];
  const float* sc   = (const float*)d_in[3];
  float* out = (float*)d_out;

  const size_t BT_BYTES  = (size_t)N_COLS * K2 * sizeof(bf16);   // 18.9 MB
  const size_t ROW_BYTES = (size_t)K2 * sizeof(bf16);            // 18 KB
  const size_t A_BYTES   = (size_t)M_ROWS * ROW_BYTES;           // 75.5 MB
  const size_t OUT_BYTES = (size_t)M_ROWS * N_COLS * sizeof(float); // 16.8 MB

  // Split-K ladder: S=4 (full chip) -> 3 -> 2, whatever fits in ws.
  int S = 0;
  for (int c = 4; c >= 2; --c)
    if (GKT % c == 0 && BT_BYTES + A_BYTES + (size_t)c * OUT_BYTES <= ws_size) {
      S = c; break;
    }

  if (S >= 2) {
    bf16*  BT    = (bf16*)d_ws;
    bf16*  Aslab = BT + (size_t)N_COLS * K2;
    float* P     = (float*)((char*)d_ws + BT_BYTES + A_BYTES);
    int kt_seg = GKT / S;

    static int coop = -1;
    if (coop < 0) {
      int v = 0, dev = 0;
      (void)hipGetDevice(&dev);
      if (hipDeviceGetAttribute(&v, hipDeviceAttributeCooperativeLaunch, dev) !=
          hipSuccess)
        v = 0;
      coop = v;
    }

    hipError_t ce = hipErrorUnknown;
    if (coop == 1) {
      void* args[] = {(void*)&x, (void*)&bw, (void*)&sw, (void*)&sc,
                      (void*)&Aslab, (void*)&BT, (void*)&P, (void*)&out,
                      (void*)&kt_seg};
      ce = hipLaunchCooperativeKernel((const void*)kan_mono, dim3(S * 64),
                                      dim3(512), args, 0, stream);
    }
    if (ce != hipSuccess) {
      // 3-dispatch fallback (R17 path, identical bodies).
      prep4<<<256, 512, 0, stream>>>(x, bw, sw, sc, Aslab, BT);
      gemm256_8p<<<S * 64, 512, 0, stream>>>(Aslab, BT, P, kt_seg);
      reduce_addN<<<2048, 256, 0, stream>>>(P, out, S);
    }
  } else {
    int SL = 0;
    for (int cand = 4096; cand >= 128; cand >>= 1)
      if (BT_BYTES + (size_t)cand * ROW_BYTES <= ws_size) { SL = cand; break; }
    if (SL) {
      bf16* BT    = (bf16*)d_ws;
      bf16* Aslab = BT + (size_t)N_COLS * K2;
      make_bt<<<(N_COLS * IN_F) / 256, 256, 0, stream>>>(bw, sw, sc, BT);
      for (int r0 = 0; r0 < M_ROWS; r0 += SL) {
        expand_a<<<(SL * IN_F) / 256, 256, 0, stream>>>(x, Aslab, r0);
        gemm_fused<<<(SL / 128) * (N_COLS / 128), 256, 0, stream>>>(
            Aslab, BT, out, out, r0, SL / 128, GKT);
      }
    } else {
      kan_fused_fallback<<<dim3(N_COLS / 128, M_ROWS / 64), 256, 0, stream>>>(
          x, bw, sw, sc, out);
    }
  }
  (void)in_sizes; (void)n_in; (void)out_size;
}

// Round 8
// 230.583 us; speedup vs baseline: 1.3310x; 1.3310x over previous
//
#include <hip/hip_runtime.h>
#include <hip/hip_bf16.h>
#include <cstdint>
#include <cstddef>

#define AS1 __attribute__((address_space(1)))
#define AS3 __attribute__((address_space(3)))

typedef __bf16 bf16;
typedef __bf16 bf16x8 __attribute__((ext_vector_type(8)));
typedef float f32x4 __attribute__((ext_vector_type(4)));

static constexpr int M_ROWS = 4096;
static constexpr int N_COLS = 1024;
static constexpr int IN_F   = 1024;
static constexpr int K2     = IN_F * 9;   // 9216: [silu(x) | 8 bases per i]
static constexpr int BK     = 32;         // fallback K-step
static constexpr int KT_CNT = K2 / BK;    // 288 (fallback)

static constexpr int GBK = 64;            // gemm K-step: rows are 128 B = 32 banks
static constexpr int GKT = K2 / GBK;      // 144

// Interface (R8 beacon): inputs f32, dict order, sizes in elements, out f32.

// Closed-form cardinal cubic B-spline over uniform knots t[j] = -2.2 + 0.4*j.
__device__ __forceinline__ void bases8(float x, float w8[8]) {
  float mf = x * 2.5f + 5.5f;           // (x - t0) / h
  int   m  = (int)floorf(mf);
  float u  = mf - (float)m;
  float u2 = u * u, u3 = u2 * u;
  float omu = 1.0f - u;
  const float s = 1.0f / 6.0f;
  float p0 = u3 * s;
  float p1 = (-3.f*u3 + 3.f*u2 + 3.f*u + 1.f) * s;
  float p2 = (3.f*u3 - 6.f*u2 + 4.f) * s;
  float p3 = omu * omu * omu * s;
  bool in = (m >= 0) && (m < 11);
#pragma unroll
  for (int j = 0; j < 8; ++j) {
    float v = 0.0f;
    v = (j == m)     ? p0 : v;
    v = (j == m - 1) ? p1 : v;
    v = (j == m - 2) ? p2 : v;
    v = (j == m - 3) ? p3 : v;
    w8[j] = in ? v : 0.0f;
  }
}

__device__ __forceinline__ void expand_body(const float* __restrict__ x,
                                            bf16* __restrict__ A, int gid, int r0) {
  int b = gid >> 10;
  int i = gid & 1023;
  float xv = x[(size_t)r0 * IN_F + (size_t)gid];
  A[(size_t)b * K2 + i] = (bf16)(xv / (1.0f + __expf(-xv)));
  float w8[8];
  bases8(xv, w8);
  bf16x8 outv;
#pragma unroll
  for (int j = 0; j < 8; ++j) outv[j] = (bf16)w8[j];
  *(bf16x8*)(A + (size_t)b * K2 + IN_F + (size_t)i * 8) = outv;
}

__device__ __forceinline__ void makebt_body(const float* __restrict__ bw,
                                            const float* __restrict__ sw,
                                            const float* __restrict__ sc,
                                            bf16* __restrict__ BT, int gid) {
  int o = gid >> 10;
  int i = gid & 1023;
  BT[(size_t)o * K2 + i] = (bf16)bw[gid];
  float scale = sc[gid];
  const float4* swp = (const float4*)(sw + (size_t)gid * 8);
  float4 a = swp[0], b4 = swp[1];
  float wv[8] = {a.x, a.y, a.z, a.w, b4.x, b4.y, b4.z, b4.w};
  bf16x8 r;
#pragma unroll
  for (int j = 0; j < 8; ++j) r[j] = (bf16)(wv[j] * scale);
  *(bf16x8*)(BT + (size_t)o * K2 + IN_F + (size_t)i * 8) = r;
}

// ---------------------------------------------------------------------------
// Kernel 1 (R15's fused prep — the session-best round's version): blocks
// [0,16384) expand A; [16384,20480) build BT.
// ---------------------------------------------------------------------------
__global__ void prep(const float* __restrict__ x, const float* __restrict__ bw,
                     const float* __restrict__ sw, const float* __restrict__ sc,
                     bf16* __restrict__ A, bf16* __restrict__ BT) {
  int bid = blockIdx.x;
  if (bid < (M_ROWS * IN_F) / 256) {
    expand_body(x, A, bid * 256 + threadIdx.x, 0);
  } else {
    makebt_body(bw, sw, sc, BT, (bid - (M_ROWS * IN_F) / 256) * 256 + threadIdx.x);
  }
}

// Standalone versions for the slab fallback path.
__global__ void expand_a(const float* __restrict__ x, bf16* __restrict__ A, int r0) {
  expand_body(x, A, blockIdx.x * blockDim.x + threadIdx.x, r0);
}
__global__ void make_bt(const float* __restrict__ bw, const float* __restrict__ sw,
                        const float* __restrict__ sc, bf16* __restrict__ BT) {
  makebt_body(bw, sw, sc, BT, blockIdx.x * blockDim.x + threadIdx.x);
}

// ---------------------------------------------------------------------------
// Kernel 2 (R19): R15's proven 8-phase 256x256 GEMM (80.5 µs / 957 TF body,
// VERBATIM through the K-loop) with an ATOMIC split-K epilogue:
//   - P planes + reduce dispatch eliminated. All 4 segs unsafeAtomicAdd
//     (HW global_atomic_add_f32) into out; out is zeroed by hipMemsetAsync
//     before this dispatch. The 4 writer blocks of each out tile share an
//     XCD (mtile%8 map) -> RMW stays L2-local. f32 ordering noise ~2^-18
//     relative, absmax budget (bf16-dominated) unaffected.
// Schedule per K-tile: 4 phases; phase = {ds_reads for quadrant | stage 1
// half-tile | barrier | lgkmcnt(0)+sched_barrier | setprio(1) 16 MFMA
// setprio(0) | barrier}. ONE vmcnt(2) per tile at P3. Swizzle chunk^=(row&7)
// both sides (0 conflicts measured). Split-K x4, XCD map b&15 (A pinned).
// ---------------------------------------------------------------------------
__global__ __launch_bounds__(512, 2) void gemm256_8p(
    const bf16* __restrict__ A, const bf16* __restrict__ BT,
    float* __restrict__ out, int kt_seg) {
  __shared__ bf16 As[2][256 * GBK];   // 2 x 32 KB
  __shared__ bf16 Bs[2][256 * GBK];   // 2 x 32 KB  (128 KB)

  const int tid  = threadIdx.x;
  const int lane = tid & 63;
  const int w    = tid >> 6;          // 0..7

  const int b     = blockIdx.x;
  const int mtile = b & 15;           // XCD = b&7 = mtile&7 -> A pinned
  const int np    = (b >> 4) & 3;
  const int seg   = b >> 6;
  const int row0  = mtile * 256;
  const int col0  = np * 256;
  const int kt0   = seg * kt_seg;

  const int srow = lane >> 3;
  const int sch  = ((lane & 7) ^ srow) * 8;

  const int r  = lane & 15;
  const int q  = lane >> 4;
  const int wm = (w >> 2) * 128;
  const int wn = (w & 3) * 64;
  const int kc0 = ((0 + q) ^ (r & 7)) * 8;
  const int kc1 = ((4 + q) ^ (r & 7)) * 8;

  const bf16* aB = A  + (size_t)row0 * K2;
  const bf16* bB = BT + (size_t)col0 * K2;

  f32x4 acc[8][4];
#pragma unroll
  for (int mt = 0; mt < 8; ++mt)
#pragma unroll
    for (int nt = 0; nt < 4; ++nt)
      acc[mt][nt] = f32x4{0.f, 0.f, 0.f, 0.f};

  auto stageA = [&](int sbuf, int h, int kt) {
#pragma unroll
    for (int t8 = 0; t8 < 2; ++t8) {
      const int rg = h * 128 + w * 16 + t8 * 8;
      const bf16* ga = aB + (size_t)(rg + srow) * K2 + kt * GBK + sch;
      __builtin_amdgcn_global_load_lds((const AS1 void*)ga,
                                       (AS3 void*)&As[sbuf][rg * GBK], 16, 0, 0);
    }
  };
  auto stageB = [&](int sbuf, int h, int kt) {
#pragma unroll
    for (int t8 = 0; t8 < 2; ++t8) {
      const int rg = h * 128 + w * 16 + t8 * 8;
      const bf16* gb = bB + (size_t)(rg + srow) * K2 + kt * GBK + sch;
      __builtin_amdgcn_global_load_lds((const AS1 void*)gb,
                                       (AS3 void*)&Bs[sbuf][rg * GBK], 16, 0, 0);
    }
  };

  // Prologue: tile0 fully + tile1's A-lo (= steady-state P3(t-1) slot).
  stageA(0, 0, kt0); stageA(0, 1, kt0);
  stageB(0, 0, kt0); stageB(0, 1, kt0);
  if (kt_seg > 1) stageA(1, 0, kt0 + 1);
  if (kt_seg > 1) asm volatile("s_waitcnt vmcnt(2)" ::: "memory");
  else            asm volatile("s_waitcnt vmcnt(0)" ::: "memory");
  __builtin_amdgcn_s_barrier();

  bf16x8 af[4][2], bfr[4][2];

  for (int t = 0; t < kt_seg; ++t) {
    const int buf = t & 1, nbuf = buf ^ 1;
    const bf16* as = As[buf];
    const bf16* bs = Bs[buf];
    const bool sN = (t + 1 < kt_seg);   // stage tile t+1 exists

    // ---- P0: reads af(mt0-3)+bfr(nt0-1) [12]; stage(t+1, A-hi); Q0 ----
#pragma unroll
    for (int j = 0; j < 4; ++j) {
      const bf16* ar = &as[(wm + j * 16 + r) * GBK];
      af[j][0] = *(const bf16x8*)&ar[kc0];
      af[j][1] = *(const bf16x8*)&ar[kc1];
    }
#pragma unroll
    for (int j = 0; j < 2; ++j) {
      const bf16* br = &bs[(wn + j * 16 + r) * GBK];
      bfr[j][0] = *(const bf16x8*)&br[kc0];
      bfr[j][1] = *(const bf16x8*)&br[kc1];
    }
    if (sN) stageA(nbuf, 1, kt0 + t + 1);
    asm volatile("s_waitcnt lgkmcnt(8)" ::: "memory");
    __builtin_amdgcn_s_barrier();
    asm volatile("s_waitcnt lgkmcnt(0)" ::: "memory");
    __builtin_amdgcn_sched_barrier(0);
    __builtin_amdgcn_s_setprio(1);
#pragma unroll
    for (int j = 0; j < 4; ++j)
#pragma unroll
      for (int n = 0; n < 2; ++n) {
        acc[j][n] = __builtin_amdgcn_mfma_f32_16x16x32_bf16(af[j][0], bfr[n][0], acc[j][n], 0, 0, 0);
        acc[j][n] = __builtin_amdgcn_mfma_f32_16x16x32_bf16(af[j][1], bfr[n][1], acc[j][n], 0, 0, 0);
      }
    __builtin_amdgcn_s_setprio(0);
    __builtin_amdgcn_s_barrier();

    // ---- P1: reads bfr(nt2-3) [4]; stage(t+1, B-lo); Q1 ----
#pragma unroll
    for (int j = 0; j < 2; ++j) {
      const bf16* br = &bs[(wn + (2 + j) * 16 + r) * GBK];
      bfr[2 + j][0] = *(const bf16x8*)&br[kc0];
      bfr[2 + j][1] = *(const bf16x8*)&br[kc1];
    }
    if (sN) stageB(nbuf, 0, kt0 + t + 1);
    __builtin_amdgcn_s_barrier();
    asm volatile("s_waitcnt lgkmcnt(0)" ::: "memory");
    __builtin_amdgcn_sched_barrier(0);
    __builtin_amdgcn_s_setprio(1);
#pragma unroll
    for (int j = 0; j < 4; ++j)
#pragma unroll
      for (int n = 0; n < 2; ++n) {
        acc[j][2 + n] = __builtin_amdgcn_mfma_f32_16x16x32_bf16(af[j][0], bfr[2 + n][0], acc[j][2 + n], 0, 0, 0);
        acc[j][2 + n] = __builtin_amdgcn_mfma_f32_16x16x32_bf16(af[j][1], bfr[2 + n][1], acc[j][2 + n], 0, 0, 0);
      }
    __builtin_amdgcn_s_setprio(0);
    __builtin_amdgcn_s_barrier();

    // ---- P2: reads af(mt4-7) [8]; stage(t+1, B-hi); Q2 ----
#pragma unroll
    for (int j = 0; j < 4; ++j) {
      const bf16* ar = &as[(wm + (4 + j) * 16 + r) * GBK];
      af[j][0] = *(const bf16x8*)&ar[kc0];
      af[j][1] = *(const bf16x8*)&ar[kc1];
    }
    if (sN) stageB(nbuf, 1, kt0 + t + 1);
    __builtin_amdgcn_s_barrier();
    asm volatile("s_waitcnt lgkmcnt(0)" ::: "memory");
    __builtin_amdgcn_sched_barrier(0);
    __builtin_amdgcn_s_setprio(1);
#pragma unroll
    for (int j = 0; j < 4; ++j)
#pragma unroll
      for (int n = 0; n < 2; ++n) {
        acc[4 + j][n] = __builtin_amdgcn_mfma_f32_16x16x32_bf16(af[j][0], bfr[n][0], acc[4 + j][n], 0, 0, 0);
        acc[4 + j][n] = __builtin_amdgcn_mfma_f32_16x16x32_bf16(af[j][1], bfr[n][1], acc[4 + j][n], 0, 0, 0);
      }
    __builtin_amdgcn_s_setprio(0);
    __builtin_amdgcn_s_barrier();

    // ---- P3: no reads; stage(t+2, A-lo) into freed buf; vmcnt; Q3 ----
    if (t + 2 < kt_seg) stageA(buf, 0, kt0 + t + 2);
    if (sN) {
      if (t + 2 < kt_seg) asm volatile("s_waitcnt vmcnt(2)" ::: "memory");
      else                asm volatile("s_waitcnt vmcnt(0)" ::: "memory");
    }
    __builtin_amdgcn_s_barrier();
    __builtin_amdgcn_s_setprio(1);
#pragma unroll
    for (int j = 0; j < 4; ++j)
#pragma unroll
      for (int n = 0; n < 2; ++n) {
        acc[4 + j][2 + n] = __builtin_amdgcn_mfma_f32_16x16x32_bf16(af[j][0], bfr[2 + n][0], acc[4 + j][2 + n], 0, 0, 0);
        acc[4 + j][2 + n] = __builtin_amdgcn_mfma_f32_16x16x32_bf16(af[j][1], bfr[2 + n][1], acc[4 + j][2 + n], 0, 0, 0);
      }
    __builtin_amdgcn_s_setprio(0);
    __builtin_amdgcn_s_barrier();
  }

  // Atomic f32 epilogue (C/D layout col = lane&15, row = (lane>>4)*4 + reg).
  // out was zeroed by hipMemsetAsync; all S segs accumulate directly.
#pragma unroll
  for (int mt = 0; mt < 8; ++mt)
#pragma unroll
    for (int nt = 0; nt < 4; ++nt)
#pragma unroll
      for (int k = 0; k < 4; ++k) {
        int row = row0 + wm + mt * 16 + q * 4 + k;
        int col = col0 + wn + nt * 16 + r;
        unsafeAtomicAdd(&out[(size_t)row * N_COLS + col], acc[mt][nt][k]);
      }
}

// ---------------------------------------------------------------------------
// Kernel 3b (R13's 128x128 gemm, kept for fallback slab path).
// ---------------------------------------------------------------------------
__global__ __launch_bounds__(256, 2) void gemm_fused(
    const bf16* __restrict__ A, const bf16* __restrict__ BT,
    float* __restrict__ d0, float* __restrict__ d1,
    int r0, int mt_cnt, int kt_seg) {
  __shared__ bf16 As[2][128 * GBK];
  __shared__ bf16 Bs[2][128 * GBK];

  const int tid  = threadIdx.x;
  const int lane = tid & 63;
  const int w    = tid >> 6;

  const int bps = mt_cnt * 8;
  int b   = blockIdx.x;
  const int seg = b / bps;
  b -= seg * bps;
  const int row0 = (b % mt_cnt) * 128;
  const int col0 = (b / mt_cnt) * 128;
  float* __restrict__ dst = seg ? d1 : d0;
  const int kt0 = seg * kt_seg;

  const int srow = lane >> 3;
  const int sch  = ((lane & 7) ^ srow) * 8;
  const int r  = lane & 15;
  const int q  = lane >> 4;
  const int wm = (w >> 1) * 64;
  const int wn = (w & 1) * 64;
  const int kc0 = ((0 + q) ^ (r & 7)) * 8;
  const int kc1 = ((4 + q) ^ (r & 7)) * 8;

  const bf16* aB = A  + (size_t)row0 * K2;
  const bf16* bB = BT + (size_t)col0 * K2;

  f32x4 acc[4][4];
#pragma unroll
  for (int mt = 0; mt < 4; ++mt)
#pragma unroll
    for (int nt = 0; nt < 4; ++nt)
      acc[mt][nt] = f32x4{0.f, 0.f, 0.f, 0.f};

  auto stage = [&](int sbuf, int kt) {
#pragma unroll
    for (int t = 0; t < 4; ++t) {
      const int rg = w * 32 + t * 8;
      const bf16* ga = aB + (size_t)(rg + srow) * K2 + kt * GBK + sch;
      __builtin_amdgcn_global_load_lds((const AS1 void*)ga,
                                       (AS3 void*)&As[sbuf][rg * GBK], 16, 0, 0);
      const bf16* gb = bB + (size_t)(rg + srow) * K2 + kt * GBK + sch;
      __builtin_amdgcn_global_load_lds((const AS1 void*)gb,
                                       (AS3 void*)&Bs[sbuf][rg * GBK], 16, 0, 0);
    }
  };

  stage(0, kt0);
  int buf = 0;
  for (int i = 0; i < kt_seg; ++i) {
    if (i + 1 < kt_seg) {
      stage(buf ^ 1, kt0 + i + 1);
      asm volatile("s_waitcnt vmcnt(8)" ::: "memory");
    } else {
      asm volatile("s_waitcnt vmcnt(0)" ::: "memory");
    }
    __builtin_amdgcn_s_barrier();
    __builtin_amdgcn_sched_barrier(0);

    const bf16* as = As[buf];
    const bf16* bs = Bs[buf];

#pragma unroll
    for (int kk = 0; kk < 2; ++kk) {
      const int kc = kk ? kc1 : kc0;
      bf16x8 af[4], bfr[4];
#pragma unroll
      for (int mt = 0; mt < 4; ++mt)
        af[mt] = *(const bf16x8*)&as[(wm + mt * 16 + r) * GBK + kc];
#pragma unroll
      for (int nt = 0; nt < 4; ++nt)
        bfr[nt] = *(const bf16x8*)&bs[(wn + nt * 16 + r) * GBK + kc];
#pragma unroll
      for (int mt = 0; mt < 4; ++mt)
#pragma unroll
        for (int nt = 0; nt < 4; ++nt)
          acc[mt][nt] = __builtin_amdgcn_mfma_f32_16x16x32_bf16(
              af[mt], bfr[nt], acc[mt][nt], 0, 0, 0);
    }
    __builtin_amdgcn_s_barrier();
    buf ^= 1;
  }

#pragma unroll
  for (int mt = 0; mt < 4; ++mt)
#pragma unroll
    for (int nt = 0; nt < 4; ++nt)
#pragma unroll
      for (int k = 0; k < 4; ++k) {
        int row = r0 + row0 + wm + mt * 16 + q * 4 + k;
        int col = col0 + wn + nt * 16 + r;
        dst[(size_t)row * N_COLS + col] = acc[mt][nt][k];
      }
}

// ---------------------------------------------------------------------------
// Kernel 4: out = p0 + p1 (slab-path split-K reduce; unused on main path).
// ---------------------------------------------------------------------------
__global__ void reduce_add(const float* __restrict__ p0,
                           const float* __restrict__ p1,
                           float* __restrict__ out) {
  int i = blockIdx.x * blockDim.x + threadIdx.x;
  f32x4 a = ((const f32x4*)p0)[i];
  f32x4 b = ((const f32x4*)p1)[i];
  ((f32x4*)out)[i] = a + b;
}

// ---------------------------------------------------------------------------
// Fallback (ws too small — not expected; SL=4096 confirmed in R9/R10).
// ---------------------------------------------------------------------------
__global__ __launch_bounds__(256) void kan_fused_fallback(
    const float* __restrict__ x, const float* __restrict__ bw,
    const float* __restrict__ sw, const float* __restrict__ sc,
    float* __restrict__ out) {
  __shared__ bf16 As[64 * BK];
  __shared__ bf16 Bs[128 * BK];
  const int tid  = threadIdx.x;
  const int lane = tid & 63;
  const int w    = tid >> 6;
  const int col0 = blockIdx.x * 128;
  const int row0 = blockIdx.y * 64;
  const int srow = tid >> 2, sq = tid & 3;
  const int r = lane & 15, q = lane >> 4, wn = w * 32;

  f32x4 acc[4][2];
#pragma unroll
  for (int mt = 0; mt < 4; ++mt)
#pragma unroll
    for (int nt = 0; nt < 2; ++nt) acc[mt][nt] = f32x4{0,0,0,0};

  for (int kt = 0; kt < KT_CNT; ++kt) {
    if (kt < 32) {
      const int cc = sq * 8;
      const float4* xp = (const float4*)(x + (size_t)(row0+srow)*IN_F + kt*BK + cc);
      float4 a = xp[0], b4 = xp[1];
      float xv[8] = {a.x,a.y,a.z,a.w,b4.x,b4.y,b4.z,b4.w};
      bf16x8 av;
#pragma unroll
      for (int j = 0; j < 8; ++j) av[j] = (bf16)(xv[j] / (1.0f + __expf(-xv[j])));
      *(bf16x8*)&As[srow * BK + cc] = av;
#pragma unroll
      for (int h = 0; h < 2; ++h) {
        const float4* bp = (const float4*)(bw + (size_t)(col0+h*64+srow)*IN_F + kt*BK + cc);
        float4 c0 = bp[0], c1 = bp[1];
        float bv[8] = {c0.x,c0.y,c0.z,c0.w,c1.x,c1.y,c1.z,c1.w};
        bf16x8 bb;
#pragma unroll
        for (int j = 0; j < 8; ++j) bb[j] = (bf16)bv[j];
        *(bf16x8*)&Bs[(h*64+srow)*BK + cc] = bb;
      }
    } else {
      const int i = (kt - 32) * 4 + sq;
      float xv = x[(size_t)(row0+srow)*IN_F + i];
      float w8[8]; bases8(xv, w8);
      bf16x8 av;
#pragma unroll
      for (int j = 0; j < 8; ++j) av[j] = (bf16)w8[j];
      *(bf16x8*)&As[srow * BK + sq * 8] = av;
#pragma unroll
      for (int h = 0; h < 2; ++h) {
        const int o = col0 + h*64 + srow;
        float s1 = sc[(size_t)o*IN_F + i];
        const float4* sp = (const float4*)(sw + ((size_t)o*IN_F + i)*8);
        float4 c0 = sp[0], c1 = sp[1];
        float wv[8] = {c0.x,c0.y,c0.z,c0.w,c1.x,c1.y,c1.z,c1.w};
        bf16x8 bb;
#pragma unroll
        for (int j = 0; j < 8; ++j) bb[j] = (bf16)(wv[j]*s1);
        *(bf16x8*)&Bs[(h*64+srow)*BK + sq*8] = bb;
      }
    }
    __syncthreads();
    bf16x8 af[4], bfr[2];
#pragma unroll
    for (int mt = 0; mt < 4; ++mt)
      af[mt] = *(const bf16x8*)&As[(mt*16+r)*BK + q*8];
#pragma unroll
    for (int nt = 0; nt < 2; ++nt)
      bfr[nt] = *(const bf16x8*)&Bs[(wn+nt*16+r)*BK + q*8];
#pragma unroll
    for (int mt = 0; mt < 4; ++mt)
#pragma unroll
      for (int nt = 0; nt < 2; ++nt)
        acc[mt][nt] = __builtin_amdgcn_mfma_f32_16x16x32_bf16(af[mt], bfr[nt], acc[mt][nt], 0,0,0);
    __syncthreads();
  }
#pragma unroll
  for (int mt = 0; mt < 4; ++mt)
#pragma unroll
    for (int nt = 0; nt < 2; ++nt)
#pragma unroll
      for (int k = 0; k < 4; ++k)
        out[(size_t)(row0+mt*16+q*4+k)*N_COLS + col0+wn+nt*16+r] = acc[mt][nt][k];
}

extern "C" void kernel_launch(void* const* d_in, const int* in_sizes, int n_in,
                              void* d_out, int out_size, void* d_ws, size_t ws_size,
                              hipStream_t stream) {
  const float* x    = (const float*)d_in[0];
  const float* bw   = (const float*)d_in[1];
  const float* sw   = (const float*)d_in[2];
  const float* sc   = (const float*)d_in[3];
  float* out = (float*)d_out;

  const size_t BT_BYTES  = (size_t)N_COLS * K2 * sizeof(bf16);   // 18.9 MB
  const size_t ROW_BYTES = (size_t)K2 * sizeof(bf16);            // 18 KB
  const size_t A_BYTES   = (size_t)M_ROWS * ROW_BYTES;           // 75.5 MB
  const size_t OUT_BYTES = (size_t)M_ROWS * N_COLS * sizeof(float); // 16.8 MB

  if (BT_BYTES + A_BYTES <= ws_size) {
    // Main path: memset(out) -> prep -> gemm (atomic split-K x4, no P/reduce).
    bf16* BT    = (bf16*)d_ws;
    bf16* Aslab = BT + (size_t)N_COLS * K2;
    hipMemsetAsync(out, 0, OUT_BYTES, stream);
    prep<<<(M_ROWS * IN_F) / 256 + (N_COLS * IN_F) / 256, 256, 0, stream>>>(
        x, bw, sw, sc, Aslab, BT);
    gemm256_8p<<<4 * 64, 512, 0, stream>>>(Aslab, BT, out, GKT / 4);
  } else {
    int SL = 0;
    for (int cand = 4096; cand >= 128; cand >>= 1)
      if (BT_BYTES + (size_t)cand * ROW_BYTES <= ws_size) { SL = cand; break; }
    if (SL) {
      bf16* BT    = (bf16*)d_ws;
      bf16* Aslab = BT + (size_t)N_COLS * K2;
      make_bt<<<(N_COLS * IN_F) / 256, 256, 0, stream>>>(bw, sw, sc, BT);
      for (int r0 = 0; r0 < M_ROWS; r0 += SL) {
        expand_a<<<(SL * IN_F) / 256, 256, 0, stream>>>(x, Aslab, r0);
        gemm_fused<<<(SL / 128) * (N_COLS / 128), 256, 0, stream>>>(
            Aslab, BT, out, out, r0, SL / 128, GKT);
      }
    } else {
      kan_fused_fallback<<<dim3(N_COLS / 128, M_ROWS / 64), 256, 0, stream>>>(
          x, bw, sw, sc, out);
    }
  }
  (void)in_sizes; (void)n_in; (void)out_size;
}

// Round 9
// 199.099 us; speedup vs baseline: 1.5415x; 1.1581x over previous
//
#include <hip/hip_runtime.h>
#include <hip/hip_bf16.h>
#include <cstdint>
#include <cstddef>

#define AS1 __attribute__((address_space(1)))
#define AS3 __attribute__((address_space(3)))

typedef __bf16 bf16;
typedef __bf16 bf16x8 __attribute__((ext_vector_type(8)));
typedef float f32x4 __attribute__((ext_vector_type(4)));

static constexpr int M_ROWS = 4096;
static constexpr int N_COLS = 1024;
static constexpr int IN_F   = 1024;
static constexpr int K2     = IN_F * 9;   // 9216: [silu(x) | 8 bases per i]
static constexpr int BK     = 32;         // fallback K-step
static constexpr int KT_CNT = K2 / BK;    // 288 (fallback)

static constexpr int GBK = 64;            // gemm K-step: rows are 128 B = 32 banks
static constexpr int GKT = K2 / GBK;      // 144

// Interface (R8 beacon): inputs f32, dict order, sizes in elements, out f32.

// Closed-form cardinal cubic B-spline over uniform knots t[j] = -2.2 + 0.4*j.
__device__ __forceinline__ void bases8(float x, float w8[8]) {
  float mf = x * 2.5f + 5.5f;           // (x - t0) / h
  int   m  = (int)floorf(mf);
  float u  = mf - (float)m;
  float u2 = u * u, u3 = u2 * u;
  float omu = 1.0f - u;
  const float s = 1.0f / 6.0f;
  float p0 = u3 * s;
  float p1 = (-3.f*u3 + 3.f*u2 + 3.f*u + 1.f) * s;
  float p2 = (3.f*u3 - 6.f*u2 + 4.f) * s;
  float p3 = omu * omu * omu * s;
  bool in = (m >= 0) && (m < 11);
#pragma unroll
  for (int j = 0; j < 8; ++j) {
    float v = 0.0f;
    v = (j == m)     ? p0 : v;
    v = (j == m - 1) ? p1 : v;
    v = (j == m - 2) ? p2 : v;
    v = (j == m - 3) ? p3 : v;
    w8[j] = in ? v : 0.0f;
  }
}

__device__ __forceinline__ void expand_body(const float* __restrict__ x,
                                            bf16* __restrict__ A, int gid, int r0) {
  int b = gid >> 10;
  int i = gid & 1023;
  float xv = x[(size_t)r0 * IN_F + (size_t)gid];
  A[(size_t)b * K2 + i] = (bf16)(xv / (1.0f + __expf(-xv)));
  float w8[8];
  bases8(xv, w8);
  bf16x8 outv;
#pragma unroll
  for (int j = 0; j < 8; ++j) outv[j] = (bf16)w8[j];
  *(bf16x8*)(A + (size_t)b * K2 + IN_F + (size_t)i * 8) = outv;
}

__device__ __forceinline__ void makebt_body(const float* __restrict__ bw,
                                            const float* __restrict__ sw,
                                            const float* __restrict__ sc,
                                            bf16* __restrict__ BT, int gid) {
  int o = gid >> 10;
  int i = gid & 1023;
  BT[(size_t)o * K2 + i] = (bf16)bw[gid];
  float scale = sc[gid];
  const float4* swp = (const float4*)(sw + (size_t)gid * 8);
  float4 a = swp[0], b4 = swp[1];
  float wv[8] = {a.x, a.y, a.z, a.w, b4.x, b4.y, b4.z, b4.w};
  bf16x8 r;
#pragma unroll
  for (int j = 0; j < 8; ++j) r[j] = (bf16)(wv[j] * scale);
  *(bf16x8*)(BT + (size_t)o * K2 + IN_F + (size_t)i * 8) = r;
}

// ---------------------------------------------------------------------------
// Kernel 1 (R15's fused prep — proven in the 201.2 µs session-best run):
// blocks [0,16384) expand A; [16384,20480) build BT.
// ---------------------------------------------------------------------------
__global__ void prep(const float* __restrict__ x, const float* __restrict__ bw,
                     const float* __restrict__ sw, const float* __restrict__ sc,
                     bf16* __restrict__ A, bf16* __restrict__ BT) {
  int bid = blockIdx.x;
  if (bid < (M_ROWS * IN_F) / 256) {
    expand_body(x, A, bid * 256 + threadIdx.x, 0);
  } else {
    makebt_body(bw, sw, sc, BT, (bid - (M_ROWS * IN_F) / 256) * 256 + threadIdx.x);
  }
}

// Standalone versions for the slab fallback path.
__global__ void expand_a(const float* __restrict__ x, bf16* __restrict__ A, int r0) {
  expand_body(x, A, blockIdx.x * blockDim.x + threadIdx.x, r0);
}
__global__ void make_bt(const float* __restrict__ bw, const float* __restrict__ sw,
                        const float* __restrict__ sc, bf16* __restrict__ BT) {
  makebt_body(bw, sw, sc, BT, blockIdx.x * blockDim.x + threadIdx.x);
}

// ---------------------------------------------------------------------------
// Kernel 2 (R20): 2-BARRIER-per-K-tile 256x256 GEMM.
// R15's 8 barriers/tile cost ~2400cy of the 5367cy/tile (floors: LDS port
// ~2816, MFMA ~2484, overlappable). Only 2 barriers are hazard-required:
//   BAR-A (after all reads of buf): before buf's A-lo is restaged for t+2.
//   BAR-B (after vmcnt-wait): staged tile data visible to ALL waves (staging
//   is cooperative; readers consume other waves' rows).
// Intra-tile ordering via COUNTED lgkm waits with the SAME register live-set
// as R15 (af[4][2] shared af03/af47 + bf01 + bf23 = 64 frag VGPRs; R16's
// spill trap avoided). ds_reads are ordinary loads -> compiler tracks deps
// (correctness); asm waits + sched_barrier(0) shape the schedule (rule #18).
// Per tile: issue af03,bf01,bf23 (16 reads) + stage(t+1 A-hi,B-lo,B-hi) ->
// lgkm(4) Q0 -> lgkm(0) Q1 -> issue af47 (8) -> lgkm(0) Q2+Q3 -> BAR-A ->
// stage(t+2 A-lo into buf) -> vmcnt(2) -> BAR-B.
// Swizzle chunk^=(row&7) both sides (0 conflicts measured). Split-K xS,
// XCD map b&15 (A pinned per XCD). Epilogue: P-plane store (R19's atomics
// measured +38µs; reverted).
// ---------------------------------------------------------------------------
__global__ __launch_bounds__(512, 2) void gemm256_8p(
    const bf16* __restrict__ A, const bf16* __restrict__ BT,
    float* __restrict__ P, int kt_seg) {
  __shared__ bf16 As[2][256 * GBK];   // 2 x 32 KB
  __shared__ bf16 Bs[2][256 * GBK];   // 2 x 32 KB  (128 KB)

  const int tid  = threadIdx.x;
  const int lane = tid & 63;
  const int w    = tid >> 6;          // 0..7

  const int b     = blockIdx.x;
  const int mtile = b & 15;           // XCD = b&7 = mtile&7 -> A pinned
  const int np    = (b >> 4) & 3;
  const int seg   = b >> 6;
  const int row0  = mtile * 256;
  const int col0  = np * 256;
  const int kt0   = seg * kt_seg;
  float* __restrict__ dst = P + (size_t)seg * M_ROWS * N_COLS;

  const int srow = lane >> 3;
  const int sch  = ((lane & 7) ^ srow) * 8;

  const int r  = lane & 15;
  const int q  = lane >> 4;
  const int wm = (w >> 2) * 128;
  const int wn = (w & 3) * 64;
  const int kc0 = ((0 + q) ^ (r & 7)) * 8;
  const int kc1 = ((4 + q) ^ (r & 7)) * 8;

  const bf16* aB = A  + (size_t)row0 * K2;
  const bf16* bB = BT + (size_t)col0 * K2;

  f32x4 acc[8][4];
#pragma unroll
  for (int mt = 0; mt < 8; ++mt)
#pragma unroll
    for (int nt = 0; nt < 4; ++nt)
      acc[mt][nt] = f32x4{0.f, 0.f, 0.f, 0.f};

  auto stageA = [&](int sbuf, int h, int kt) {
#pragma unroll
    for (int t8 = 0; t8 < 2; ++t8) {
      const int rg = h * 128 + w * 16 + t8 * 8;
      const bf16* ga = aB + (size_t)(rg + srow) * K2 + kt * GBK + sch;
      __builtin_amdgcn_global_load_lds((const AS1 void*)ga,
                                       (AS3 void*)&As[sbuf][rg * GBK], 16, 0, 0);
    }
  };
  auto stageB = [&](int sbuf, int h, int kt) {
#pragma unroll
    for (int t8 = 0; t8 < 2; ++t8) {
      const int rg = h * 128 + w * 16 + t8 * 8;
      const bf16* gb = bB + (size_t)(rg + srow) * K2 + kt * GBK + sch;
      __builtin_amdgcn_global_load_lds((const AS1 void*)gb,
                                       (AS3 void*)&Bs[sbuf][rg * GBK], 16, 0, 0);
    }
  };

  // Prologue: tile0 fully + tile1's A-lo (steady-state slot), then BAR-B.
  stageA(0, 0, kt0); stageA(0, 1, kt0);
  stageB(0, 0, kt0); stageB(0, 1, kt0);
  if (kt_seg > 1) stageA(1, 0, kt0 + 1);
  if (kt_seg > 1) asm volatile("s_waitcnt vmcnt(2)" ::: "memory");
  else            asm volatile("s_waitcnt vmcnt(0)" ::: "memory");
  __builtin_amdgcn_s_barrier();

  bf16x8 af[4][2], bf01[2][2], bf23[2][2];

  for (int t = 0; t < kt_seg; ++t) {
    const int buf = t & 1, nbuf = buf ^ 1;
    const bf16* as = As[buf];
    const bf16* bs = Bs[buf];
    const bool sN = (t + 1 < kt_seg);

    // Batch-1 reads (issue order matters for counted lgkm): af03(8), bf01(4),
    // bf23(4).
#pragma unroll
    for (int j = 0; j < 4; ++j) {
      const bf16* ar = &as[(wm + j * 16 + r) * GBK];
      af[j][0] = *(const bf16x8*)&ar[kc0];
      af[j][1] = *(const bf16x8*)&ar[kc1];
    }
#pragma unroll
    for (int j = 0; j < 2; ++j) {
      const bf16* br = &bs[(wn + j * 16 + r) * GBK];
      bf01[j][0] = *(const bf16x8*)&br[kc0];
      bf01[j][1] = *(const bf16x8*)&br[kc1];
    }
#pragma unroll
    for (int j = 0; j < 2; ++j) {
      const bf16* br = &bs[(wn + (2 + j) * 16 + r) * GBK];
      bf23[j][0] = *(const bf16x8*)&br[kc0];
      bf23[j][1] = *(const bf16x8*)&br[kc1];
    }
    // Stage t+1 (A-hi, B-lo, B-hi) into nbuf — vmcnt traffic, lgkm-invisible.
    if (sN) {
      stageA(nbuf, 1, kt0 + t + 1);
      stageB(nbuf, 0, kt0 + t + 1);
      stageB(nbuf, 1, kt0 + t + 1);
    }

    // Q0: af03 x bf01 (needs first 12 reads; 4 may stay in flight).
    asm volatile("s_waitcnt lgkmcnt(4)" ::: "memory");
    __builtin_amdgcn_sched_barrier(0);
    __builtin_amdgcn_s_setprio(1);
#pragma unroll
    for (int j = 0; j < 4; ++j)
#pragma unroll
      for (int n = 0; n < 2; ++n) {
        acc[j][n] = __builtin_amdgcn_mfma_f32_16x16x32_bf16(af[j][0], bf01[n][0], acc[j][n], 0, 0, 0);
        acc[j][n] = __builtin_amdgcn_mfma_f32_16x16x32_bf16(af[j][1], bf01[n][1], acc[j][n], 0, 0, 0);
      }
    __builtin_amdgcn_s_setprio(0);

    // Q1: af03 x bf23.
    asm volatile("s_waitcnt lgkmcnt(0)" ::: "memory");
    __builtin_amdgcn_sched_barrier(0);
    __builtin_amdgcn_s_setprio(1);
#pragma unroll
    for (int j = 0; j < 4; ++j)
#pragma unroll
      for (int n = 0; n < 2; ++n) {
        acc[j][2 + n] = __builtin_amdgcn_mfma_f32_16x16x32_bf16(af[j][0], bf23[n][0], acc[j][2 + n], 0, 0, 0);
        acc[j][2 + n] = __builtin_amdgcn_mfma_f32_16x16x32_bf16(af[j][1], bf23[n][1], acc[j][2 + n], 0, 0, 0);
      }
    __builtin_amdgcn_s_setprio(0);

    // Batch-2 reads: af47 overwrites af (same live-set as R15).
#pragma unroll
    for (int j = 0; j < 4; ++j) {
      const bf16* ar = &as[(wm + (4 + j) * 16 + r) * GBK];
      af[j][0] = *(const bf16x8*)&ar[kc0];
      af[j][1] = *(const bf16x8*)&ar[kc1];
    }
    // Q2+Q3: af47 x {bf23, bf01}.
    asm volatile("s_waitcnt lgkmcnt(0)" ::: "memory");
    __builtin_amdgcn_sched_barrier(0);
    __builtin_amdgcn_s_setprio(1);
#pragma unroll
    for (int j = 0; j < 4; ++j)
#pragma unroll
      for (int n = 0; n < 2; ++n) {
        acc[4 + j][2 + n] = __builtin_amdgcn_mfma_f32_16x16x32_bf16(af[j][0], bf23[n][0], acc[4 + j][2 + n], 0, 0, 0);
        acc[4 + j][2 + n] = __builtin_amdgcn_mfma_f32_16x16x32_bf16(af[j][1], bf23[n][1], acc[4 + j][2 + n], 0, 0, 0);
      }
#pragma unroll
    for (int j = 0; j < 4; ++j)
#pragma unroll
      for (int n = 0; n < 2; ++n) {
        acc[4 + j][n] = __builtin_amdgcn_mfma_f32_16x16x32_bf16(af[j][0], bf01[n][0], acc[4 + j][n], 0, 0, 0);
        acc[4 + j][n] = __builtin_amdgcn_mfma_f32_16x16x32_bf16(af[j][1], bf01[n][1], acc[4 + j][n], 0, 0, 0);
      }
    __builtin_amdgcn_s_setprio(0);

    // BAR-A: all waves' reads of buf done -> its A-lo may be restaged.
    __builtin_amdgcn_s_barrier();
    if (t + 2 < kt_seg) stageA(buf, 0, kt0 + t + 2);
    if (sN) {
      if (t + 2 < kt_seg) asm volatile("s_waitcnt vmcnt(2)" ::: "memory");
      else                asm volatile("s_waitcnt vmcnt(0)" ::: "memory");
      // BAR-B: tile t+1 fully landed and visible to all waves.
      __builtin_amdgcn_s_barrier();
    }
  }

  // f32 epilogue: C/D layout col = lane&15, row = (lane>>4)*4 + reg
#pragma unroll
  for (int mt = 0; mt < 8; ++mt)
#pragma unroll
    for (int nt = 0; nt < 4; ++nt)
#pragma unroll
      for (int k = 0; k < 4; ++k) {
        int row = row0 + wm + mt * 16 + q * 4 + k;
        int col = col0 + wn + nt * 16 + r;
        dst[(size_t)row * N_COLS + col] = acc[mt][nt][k];
      }
}

// ---------------------------------------------------------------------------
// Kernel 3: out = sum of S partial planes, f32x4 vectorized (R15 proven).
// ---------------------------------------------------------------------------
__global__ void reduce_addN(const float* __restrict__ P,
                            float* __restrict__ out, int segs) {
  size_t i = (size_t)blockIdx.x * blockDim.x + threadIdx.x;
  const f32x4* p = (const f32x4*)P;
  const size_t plane = (size_t)M_ROWS * N_COLS / 4;
  f32x4 a = p[i];
  for (int s = 1; s < segs; ++s) a += p[(size_t)s * plane + i];
  ((f32x4*)out)[i] = a;
}

// ---------------------------------------------------------------------------
// Kernel 3b (R13's 128x128 gemm, kept for fallback slab path).
// ---------------------------------------------------------------------------
__global__ __launch_bounds__(256, 2) void gemm_fused(
    const bf16* __restrict__ A, const bf16* __restrict__ BT,
    float* __restrict__ d0, float* __restrict__ d1,
    int r0, int mt_cnt, int kt_seg) {
  __shared__ bf16 As[2][128 * GBK];
  __shared__ bf16 Bs[2][128 * GBK];

  const int tid  = threadIdx.x;
  const int lane = tid & 63;
  const int w    = tid >> 6;

  const int bps = mt_cnt * 8;
  int b   = blockIdx.x;
  const int seg = b / bps;
  b -= seg * bps;
  const int row0 = (b % mt_cnt) * 128;
  const int col0 = (b / mt_cnt) * 128;
  float* __restrict__ dst = seg ? d1 : d0;
  const int kt0 = seg * kt_seg;

  const int srow = lane >> 3;
  const int sch  = ((lane & 7) ^ srow) * 8;
  const int r  = lane & 15;
  const int q  = lane >> 4;
  const int wm = (w >> 1) * 64;
  const int wn = (w & 1) * 64;
  const int kc0 = ((0 + q) ^ (r & 7)) * 8;
  const int kc1 = ((4 + q) ^ (r & 7)) * 8;

  const bf16* aB = A  + (size_t)row0 * K2;
  const bf16* bB = BT + (size_t)col0 * K2;

  f32x4 acc[4][4];
#pragma unroll
  for (int mt = 0; mt < 4; ++mt)
#pragma unroll
    for (int nt = 0; nt < 4; ++nt)
      acc[mt][nt] = f32x4{0.f, 0.f, 0.f, 0.f};

  auto stage = [&](int sbuf, int kt) {
#pragma unroll
    for (int t = 0; t < 4; ++t) {
      const int rg = w * 32 + t * 8;
      const bf16* ga = aB + (size_t)(rg + srow) * K2 + kt * GBK + sch;
      __builtin_amdgcn_global_load_lds((const AS1 void*)ga,
                                       (AS3 void*)&As[sbuf][rg * GBK], 16, 0, 0);
      const bf16* gb = bB + (size_t)(rg + srow) * K2 + kt * GBK + sch;
      __builtin_amdgcn_global_load_lds((const AS1 void*)gb,
                                       (AS3 void*)&Bs[sbuf][rg * GBK], 16, 0, 0);
    }
  };

  stage(0, kt0);
  int buf = 0;
  for (int i = 0; i < kt_seg; ++i) {
    if (i + 1 < kt_seg) {
      stage(buf ^ 1, kt0 + i + 1);
      asm volatile("s_waitcnt vmcnt(8)" ::: "memory");
    } else {
      asm volatile("s_waitcnt vmcnt(0)" ::: "memory");
    }
    __builtin_amdgcn_s_barrier();
    __builtin_amdgcn_sched_barrier(0);

    const bf16* as = As[buf];
    const bf16* bs = Bs[buf];

#pragma unroll
    for (int kk = 0; kk < 2; ++kk) {
      const int kc = kk ? kc1 : kc0;
      bf16x8 af[4], bfr[4];
#pragma unroll
      for (int mt = 0; mt < 4; ++mt)
        af[mt] = *(const bf16x8*)&as[(wm + mt * 16 + r) * GBK + kc];
#pragma unroll
      for (int nt = 0; nt < 4; ++nt)
        bfr[nt] = *(const bf16x8*)&bs[(wn + nt * 16 + r) * GBK + kc];
#pragma unroll
      for (int mt = 0; mt < 4; ++mt)
#pragma unroll
        for (int nt = 0; nt < 4; ++nt)
          acc[mt][nt] = __builtin_amdgcn_mfma_f32_16x16x32_bf16(
              af[mt], bfr[nt], acc[mt][nt], 0, 0, 0);
    }
    __builtin_amdgcn_s_barrier();
    buf ^= 1;
  }

#pragma unroll
  for (int mt = 0; mt < 4; ++mt)
#pragma unroll
    for (int nt = 0; nt < 4; ++nt)
#pragma unroll
      for (int k = 0; k < 4; ++k) {
        int row = r0 + row0 + wm + mt * 16 + q * 4 + k;
        int col = col0 + wn + nt * 16 + r;
        dst[(size_t)row * N_COLS + col] = acc[mt][nt][k];
      }
}

// ---------------------------------------------------------------------------
// Fallback (ws too small — not expected; SL=4096 confirmed in R9/R10).
// ---------------------------------------------------------------------------
__global__ __launch_bounds__(256) void kan_fused_fallback(
    const float* __restrict__ x, const float* __restrict__ bw,
    const float* __restrict__ sw, const float* __restrict__ sc,
    float* __restrict__ out) {
  __shared__ bf16 As[64 * BK];
  __shared__ bf16 Bs[128 * BK];
  const int tid  = threadIdx.x;
  const int lane = tid & 63;
  const int w    = tid >> 6;
  const int col0 = blockIdx.x * 128;
  const int row0 = blockIdx.y * 64;
  const int srow = tid >> 2, sq = tid & 3;
  const int r = lane & 15, q = lane >> 4, wn = w * 32;

  f32x4 acc[4][2];
#pragma unroll
  for (int mt = 0; mt < 4; ++mt)
#pragma unroll
    for (int nt = 0; nt < 2; ++nt) acc[mt][nt] = f32x4{0,0,0,0};

  for (int kt = 0; kt < KT_CNT; ++kt) {
    if (kt < 32) {
      const int cc = sq * 8;
      const float4* xp = (const float4*)(x + (size_t)(row0+srow)*IN_F + kt*BK + cc);
      float4 a = xp[0], b4 = xp[1];
      float xv[8] = {a.x,a.y,a.z,a.w,b4.x,b4.y,b4.z,b4.w};
      bf16x8 av;
#pragma unroll
      for (int j = 0; j < 8; ++j) av[j] = (bf16)(xv[j] / (1.0f + __expf(-xv[j])));
      *(bf16x8*)&As[srow * BK + cc] = av;
#pragma unroll
      for (int h = 0; h < 2; ++h) {
        const float4* bp = (const float4*)(bw + (size_t)(col0+h*64+srow)*IN_F + kt*BK + cc);
        float4 c0 = bp[0], c1 = bp[1];
        float bv[8] = {c0.x,c0.y,c0.z,c0.w,c1.x,c1.y,c1.z,c1.w};
        bf16x8 bb;
#pragma unroll
        for (int j = 0; j < 8; ++j) bb[j] = (bf16)bv[j];
        *(bf16x8*)&Bs[(h*64+srow)*BK + cc] = bb;
      }
    } else {
      const int i = (kt - 32) * 4 + sq;
      float xv = x[(size_t)(row0+srow)*IN_F + i];
      float w8[8]; bases8(xv, w8);
      bf16x8 av;
#pragma unroll
      for (int j = 0; j < 8; ++j) av[j] = (bf16)w8[j];
      *(bf16x8*)&As[srow * BK + sq * 8] = av;
#pragma unroll
      for (int h = 0; h < 2; ++h) {
        const int o = col0 + h*64 + srow;
        float s1 = sc[(size_t)o*IN_F + i];
        const float4* sp = (const float4*)(sw + ((size_t)o*IN_F + i)*8);
        float4 c0 = sp[0], c1 = sp[1];
        float wv[8] = {c0.x,c0.y,c0.z,c0.w,c1.x,c1.y,c1.z,c1.w};
        bf16x8 bb;
#pragma unroll
        for (int j = 0; j < 8; ++j) bb[j] = (bf16)(wv[j]*s1);
        *(bf16x8*)&Bs[(h*64+srow)*BK + sq*8] = bb;
      }
    }
    __syncthreads();
    bf16x8 af[4], bfr[2];
#pragma unroll
    for (int mt = 0; mt < 4; ++mt)
      af[mt] = *(const bf16x8*)&As[(mt*16+r)*BK + q*8];
#pragma unroll
    for (int nt = 0; nt < 2; ++nt)
      bfr[nt] = *(const bf16x8*)&Bs[(wn+nt*16+r)*BK + q*8];
#pragma unroll
    for (int mt = 0; mt < 4; ++mt)
#pragma unroll
      for (int nt = 0; nt < 2; ++nt)
        acc[mt][nt] = __builtin_amdgcn_mfma_f32_16x16x32_bf16(af[mt], bfr[nt], acc[mt][nt], 0,0,0);
    __syncthreads();
  }
#pragma unroll
  for (int mt = 0; mt < 4; ++mt)
#pragma unroll
    for (int nt = 0; nt < 2; ++nt)
#pragma unroll
      for (int k = 0; k < 4; ++k)
        out[(size_t)(row0+mt*16+q*4+k)*N_COLS + col0+wn+nt*16+r] = acc[mt][nt][k];
}

extern "C" void kernel_launch(void* const* d_in, const int* in_sizes, int n_in,
                              void* d_out, int out_size, void* d_ws, size_t ws_size,
                              hipStream_t stream) {
  const float* x    = (const float*)d_in[0];
  const float* bw   = (const float*)d_in[1];
  const float* sw   = (const float*)d_in[2];
  const float* sc   = (const float*)d_in[3];
  float* out = (float*)d_out;

  const size_t BT_BYTES  = (size_t)N_COLS * K2 * sizeof(bf16);   // 18.9 MB
  const size_t ROW_BYTES = (size_t)K2 * sizeof(bf16);            // 18 KB
  const size_t A_BYTES   = (size_t)M_ROWS * ROW_BYTES;           // 75.5 MB
  const size_t OUT_BYTES = (size_t)M_ROWS * N_COLS * sizeof(float); // 16.8 MB

  // Split-K ladder: S=4 (full chip) -> 3 -> 2, whatever fits in ws.
  int S = 0;
  for (int c = 4; c >= 2; --c)
    if (GKT % c == 0 && BT_BYTES + A_BYTES + (size_t)c * OUT_BYTES <= ws_size) {
      S = c; break;
    }

  if (S >= 2) {
    bf16*  BT    = (bf16*)d_ws;
    bf16*  Aslab = BT + (size_t)N_COLS * K2;
    float* P     = (float*)((char*)d_ws + BT_BYTES + A_BYTES);
    prep<<<(M_ROWS * IN_F) / 256 + (N_COLS * IN_F) / 256, 256, 0, stream>>>(
        x, bw, sw, sc, Aslab, BT);
    gemm256_8p<<<S * 64, 512, 0, stream>>>(Aslab, BT, P, GKT / S);
    reduce_addN<<<(M_ROWS * N_COLS) / (4 * 256), 256, 0, stream>>>(P, out, S);
  } else {
    int SL = 0;
    for (int cand = 4096; cand >= 128; cand >>= 1)
      if (BT_BYTES + (size_t)cand * ROW_BYTES <= ws_size) { SL = cand; break; }
    if (SL) {
      bf16* BT    = (bf16*)d_ws;
      bf16* Aslab = BT + (size_t)N_COLS * K2;
      make_bt<<<(N_COLS * IN_F) / 256, 256, 0, stream>>>(bw, sw, sc, BT);
      for (int r0 = 0; r0 < M_ROWS; r0 += SL) {
        expand_a<<<(SL * IN_F) / 256, 256, 0, stream>>>(x, Aslab, r0);
        gemm_fused<<<(SL / 128) * (N_COLS / 128), 256, 0, stream>>>(
            Aslab, BT, out, out, r0, SL / 128, GKT);
      }
    } else {
      kan_fused_fallback<<<dim3(N_COLS / 128, M_ROWS / 64), 256, 0, stream>>>(
          x, bw, sw, sc, out);
    }
  }
  (void)in_sizes; (void)n_in; (void)out_size;
}